// Round 12
// baseline (311.908 us; speedup 1.0000x reference)
//
#include <hip/hip_runtime.h>

typedef short s16x8 __attribute__((ext_vector_type(8)));  // 8 bf16
typedef float f32x4 __attribute__((ext_vector_type(4)));  // 16x16 MFMA acc

#define CODES_ELEMS 8388608   // 16*1024*512
#define N_ROWS      131072    // 16*1024*8
#define IDX_OFF     CODES_ELEMS
#define LOSS_OFF    (CODES_ELEMS + N_ROWS)

// d_ws: [0,4) loss acc; [64,8256) cc[2048];
// [8448,532736) cbs bf16-split tiled codebook [chunk32][seg4][ct4][lane64][8]
//   seg 0,1 = c1 dims 0-31/32-63; seg 2,3 = c2 exact residual dims 0-31/32-63
#define WS_LOSS 0
#define WS_CC   64
#define WS_CBS  8448
// validated r13-r20 (absmax 0 x8): packed-min + margin + offset constants
#define MARGIN_T 0.0625f
#define DIST_OFF 512.0f

__device__ __forceinline__ float bf2f(unsigned short h) { return __uint_as_float(((unsigned)h) << 16); }
__device__ __forceinline__ unsigned short f2bf(float f) {   // RNE
  unsigned u = __float_as_uint(f);
  u += 0x7fffu + ((u >> 16) & 1u);
  return (unsigned short)(u >> 16);
}

// Prep (validated r16-r20): bf16-split codebook into 16x16x32 B-fragment
// layout (chunk 64 codes / ct-width 4) + cc[k] butterfly.
__global__ __launch_bounds__(256) void vq_prep(const float* __restrict__ cb,
                                               float* __restrict__ cc,
                                               unsigned short* __restrict__ cbs,
                                               float* __restrict__ loss) {
  int t = threadIdx.x;
  if (blockIdx.x == 0 && t == 0) loss[0] = 0.f;
  int e = blockIdx.x * 256 + t;   // 1024*256 = 2048 codes * 128 K-elems
  int k = e >> 7, K = e & 127;
  int s = K >> 5, rem = K & 31, q = rem >> 3, j = rem & 7;
  int d = (s < 2) ? K : (K - 64);
  float c = cb[k * 64 + d];
  unsigned short c1 = f2bf(c);
  unsigned short val = (s < 2) ? c1 : f2bf(c - bf2f(c1));  // exact residual split
  int chunk = k >> 6, ct = (k >> 4) & 3, n = k & 15;
  cbs[(((size_t)(chunk * 4 + s) * 4 + ct) * 64 + (q * 16 + n)) * 8 + j] = val;
  float sq = c * c;
  #pragma unroll
  for (int m = 1; m < 64; m <<= 1) sq += __shfl_xor(sq, m, 64);
  if ((t & 63) == 0) cc[k] = sq;
}

// Mega-kernel r21 = r20 (barrier-free global-B K-loop, absmax 0, VGPR 96,
// no spill) at doubled residency: 128 rows/block, 2 tiles/wave, grid 1024.
// r20 stuck at ~34% K-loop MfmaUtil with 2 blocks/CU (8 waves) — dependent
// 6-MFMA chains + acc->VALU min-updates lack TLP at 2 waves/SIMD. r18's
// LDS-BW objection to 128-row blocks is void now: B comes from L1 (16KB
// chunk resident; ~70B/cyc needed at 4 blocks/CU). LDS 12.8KB, VGPR ~80
// -> 4 blocks/CU = 16 waves/CU. Math byte-identical to r20.
__global__ __launch_bounds__(256) void VQQuantizer_30064771072206_kernel(
    const float* __restrict__ zf, const float* __restrict__ cb,
    const unsigned short* __restrict__ cbs, const float* __restrict__ cc,
    float* __restrict__ loss, float* __restrict__ out)
{
  __shared__ __align__(16) float cc_l[2048];     // 8KB, read in K-loop + rescore
  __shared__ int   idx_l[128];
  __shared__ int   flg[128];
  __shared__ int   nf;
  __shared__ __align__(16) float zl[8][68];
  __shared__ float zz_l[8];
  __shared__ int   rows_s[8];
  __shared__ float rv[4][8];
  __shared__ int   ri[4][8];
  __shared__ float wsum[4];

  const int t = threadIdx.x, w = t >> 6, l = t & 63;
  const int col = l & 15, q = l >> 4;
  const int R0 = blockIdx.x * 128;
  const float4* zf4 = (const float4*)zf;
  const float4* cb4 = (const float4*)cb;

  // prologue: load full cc into LDS
  #pragma unroll
  for (int i = 0; i < 2; ++i)
    ((float4*)cc_l)[i * 256 + t] = ((const float4*)cc)[i * 256 + t];

  // A-fragments (r12-validated 2-tile mapping): lane holds A[m=l&15][k=q*8+j];
  // row = R0 + tile*64 + 16w + col; seg s covers dims s*32 + q*8 + j.
  s16x8 az1[2][2], az2[2][2];   // [tile][seg]: bf16(-2z) and exact residual
  #pragma unroll
  for (int tile = 0; tile < 2; ++tile) {
    int row = R0 + tile * 64 + 16 * w + col;
    const float4* zr = zf4 + (size_t)row * 16;
    #pragma unroll
    for (int s = 0; s < 2; ++s) {
      float4 u0 = zr[s * 8 + q * 2];
      float4 u1 = zr[s * 8 + q * 2 + 1];
      float m2[8] = {-2.f*u0.x, -2.f*u0.y, -2.f*u0.z, -2.f*u0.w,
                     -2.f*u1.x, -2.f*u1.y, -2.f*u1.z, -2.f*u1.w};
      #pragma unroll
      for (int j = 0; j < 8; ++j) {
        unsigned short h1 = f2bf(m2[j]);
        unsigned short h2 = f2bf(m2[j] - bf2f(h1));
        az1[tile][s][j] = (short)h1;
        az2[tile][s][j] = (short)h2;
      }
    }
  }

  unsigned p1[2][4], p2[2][4];   // packed (trunc dist | pid): best / second
  #pragma unroll
  for (int tile = 0; tile < 2; ++tile)
    #pragma unroll
    for (int r = 0; r < 4; ++r) { p1[tile][r] = 0xFFFFFFFFu; p2[tile][r] = 0xFFFFFFFFu; }

  __syncthreads();   // cc_l visible (the ONLY barrier before phase 2)

  // ---- K-loop: barrier-free; B-frags straight from L1/L2-resident cbs.
  // frag(s,ct) at chunk*8192 + s*2048 + ct*512 + l*8 elements (r20-validated).
  #pragma unroll 1
  for (int chunk = 0; chunk < 32; ++chunk) {
    const unsigned short* gb = cbs + (size_t)chunk * 8192 + (size_t)l * 8;
    const float* ccc = &cc_l[chunk * 64 + col];
    #pragma unroll 2                // cap the load-hoisting window (r15 lesson)
    for (int ct = 0; ct < 4; ++ct) {
      float nh = DIST_OFF + ccc[ct * 16];
      const unsigned short* base = gb + ct * 512;
      s16x8 b0 = *(const s16x8*)(base + 0 * 2048);   // c1 dims 0-31
      s16x8 b1 = *(const s16x8*)(base + 1 * 2048);   // c1 dims 32-63
      s16x8 b2 = *(const s16x8*)(base + 2 * 2048);   // c2 dims 0-31
      s16x8 b3 = *(const s16x8*)(base + 3 * 2048);   // c2 dims 32-63
      unsigned pid = (unsigned)(chunk * 4 + ct);     // 7 bits, ascending codes
      #pragma unroll
      for (int tile = 0; tile < 2; ++tile) {
        f32x4 acc; acc[0] = nh; acc[1] = nh; acc[2] = nh; acc[3] = nh;
        acc = __builtin_amdgcn_mfma_f32_16x16x32_bf16(az1[tile][0], b0, acc, 0, 0, 0);
        acc = __builtin_amdgcn_mfma_f32_16x16x32_bf16(az1[tile][1], b1, acc, 0, 0, 0);
        acc = __builtin_amdgcn_mfma_f32_16x16x32_bf16(az1[tile][0], b2, acc, 0, 0, 0);
        acc = __builtin_amdgcn_mfma_f32_16x16x32_bf16(az1[tile][1], b3, acc, 0, 0, 0);
        acc = __builtin_amdgcn_mfma_f32_16x16x32_bf16(az2[tile][0], b0, acc, 0, 0, 0);
        acc = __builtin_amdgcn_mfma_f32_16x16x32_bf16(az2[tile][1], b1, acc, 0, 0, 0);
        #pragma unroll
        for (int r = 0; r < 4; ++r) {   // packed (best, second): 4 int ops
          unsigned pd = (__float_as_uint(acc[r]) & 0xFFFFFF80u) | pid;
          unsigned mx = p1[tile][r] > pd ? p1[tile][r] : pd;
          p2[tile][r] = p2[tile][r] < mx ? p2[tile][r] : mx;
          p1[tile][r] = p1[tile][r] < pd ? p1[tile][r] : pd;
        }
      }
    }
  }

  // ---- phase 2: unpack + merge across the 16 lanes of each row group ----
  if (t == 0) nf = 0;
  __syncthreads();
  #pragma unroll
  for (int tile = 0; tile < 2; ++tile) {
    #pragma unroll
    for (int r = 0; r < 4; ++r) {
      float a   = __uint_as_float(p1[tile][r] & 0xFFFFFF80u);
      int   ia  = (int)(p1[tile][r] & 127u) * 16 + col;   // code = pid*16 + col
      float b2v = __uint_as_float(p2[tile][r] & 0xFFFFFF80u);
      #pragma unroll
      for (int m = 1; m < 16; m <<= 1) {
        float oa = __shfl_xor(a, m, 64);
        int   oi = __shfl_xor(ia, m, 64);
        float ob = __shfl_xor(b2v, m, 64);
        float hv = fmaxf(a, oa);
        b2v = fminf(fminf(b2v, ob), hv);
        bool take = (oa < a) || (oa == a && oi < ia);
        a = take ? oa : a; ia = take ? oi : ia;
      }
      if (col == 0) {   // C/D: col=l&15, row=(l>>4)*4+r [m89, validated]
        int rl = tile * 64 + 16 * w + q * 4 + r;
        idx_l[rl] = ia;
        if (b2v - a < MARGIN_T) {
          int p = atomicAdd(&nf, 1);
          flg[p] = rl;
        }
      }
    }
  }
  __syncthreads();

  // ---- phase 3: exact fp32 rescore of flagged rows (validated inner chain;
  //      dq-loop unroll capped at 4 to keep register pressure below K-loop) ----
  int count = nf;
  for (int itb = 0; itb * 8 < count; ++itb) {
    if (itb) __syncthreads();
    if (t < 8) {
      int ii = itb * 8 + t;
      rows_s[t] = flg[ii < count ? ii : count - 1];  // tail dup: benign rewrite
    }
    __syncthreads();
    if (t < 128) {
      int r = t >> 4, dq = t & 15;
      *(float4*)&zl[r][dq * 4] = zf4[(size_t)(R0 + rows_s[r]) * 16 + dq];
    }
    __syncthreads();
    if (t < 8) {                          // zz: sequential-d np chain
      float s = 0.f;
      for (int d = 0; d < 64; ++d) { float v = zl[t][d]; s += v * v; }
      zz_l[t] = s;
    }
    __syncthreads();

    float bv[8]; int bi[8];
    #pragma unroll
    for (int r = 0; r < 8; ++r) { bv[r] = 3.402823466e38f; bi[r] = 0; }
    #pragma unroll 1
    for (int o = 0; o < 8; ++o) {         // thread's codes ascending: o*256+t
      int c = o * 256 + t;
      const float4* cr = cb4 + (size_t)c * 16;
      float a[8];
      #pragma unroll
      for (int r = 0; r < 8; ++r) a[r] = 0.f;
      #pragma unroll 4                    // cap hoisted cv regs
      for (int dq = 0; dq < 16; ++dq) {
        float4 cv = cr[dq];
        #pragma unroll
        for (int r = 0; r < 8; ++r) {
          float4 z4 = *(const float4*)&zl[r][dq * 4];
          a[r] += z4.x * cv.x;
          a[r] += z4.y * cv.y;
          a[r] += z4.z * cv.z;
          a[r] += z4.w * cv.w;
        }
      }
      float ccv = cc_l[c];
      #pragma unroll
      for (int r = 0; r < 8; ++r) {
        float t0 = zz_l[r] - 2.0f * a[r];
        float dist = t0 + ccv;
        if (dist < bv[r]) { bv[r] = dist; bi[r] = c; }
      }
    }
    #pragma unroll
    for (int r = 0; r < 8; ++r) {
      float v = bv[r]; int idx = bi[r];
      #pragma unroll
      for (int m = 1; m < 64; m <<= 1) {
        float ov = __shfl_xor(v, m, 64); int oi = __shfl_xor(idx, m, 64);
        if (ov < v || (ov == v && oi < idx)) { v = ov; idx = oi; }
      }
      if (l == 0) { rv[w][r] = v; ri[w][r] = idx; }
    }
    __syncthreads();
    if (t < 8) {
      float fv = rv[0][t]; int fi = ri[0][t];
      #pragma unroll
      for (int k = 1; k < 4; ++k) {
        if (rv[k][t] < fv || (rv[k][t] == fv && ri[k][t] < fi)) { fv = rv[k][t]; fi = ri[k][t]; }
      }
      idx_l[rows_s[t]] = fi;
    }
  }
  __syncthreads();

  // ---- phase 4: epilogue for this block's 128 rows (unroll capped, r17) ----
  float4* out4 = (float4*)out;
  float lsum = 0.f;
  #pragma unroll 2
  for (int i = 0; i < 8; ++i) {
    int f = i * 256 + t;
    int row = f >> 4, dq = f & 15;
    int k = idx_l[row];
    float4 qv = cb4[(size_t)k * 16 + dq];
    float4 zv = zf4[(size_t)(R0 + row) * 16 + dq];
    float dx = qv.x - zv.x, dy = qv.y - zv.y, dz = qv.z - zv.z, dw = qv.w - zv.w;
    float4 st; st.x = zv.x + dx; st.y = zv.y + dy; st.z = zv.z + dz; st.w = zv.w + dw;
    out4[(size_t)(R0 + row) * 16 + dq] = st;
    lsum += dx * dx; lsum += dy * dy; lsum += dz * dz; lsum += dw * dw;
  }
  if (t < 128) out[IDX_OFF + R0 + t] = (float)idx_l[t];
  #pragma unroll
  for (int m = 1; m < 64; m <<= 1) lsum += __shfl_xor(lsum, m, 64);
  if (l == 0) wsum[w] = lsum;
  __syncthreads();
  if (t == 0) atomicAdd(loss, wsum[0] + wsum[1] + wsum[2] + wsum[3]);
}

__global__ void vq_finalize(const float* __restrict__ loss, float* __restrict__ out) {
  out[LOSS_OFF] = loss[0] * (1.f / 8388608.f);
}

extern "C" void kernel_launch(void* const* d_in, const int* in_sizes, int n_in,
                              void* d_out, int out_size, void* d_ws, size_t ws_size,
                              hipStream_t stream) {
  const float* z  = (const float*)d_in[0];
  const float* cb = (const float*)d_in[1];
  float* out = (float*)d_out;
  float* loss = (float*)((char*)d_ws + WS_LOSS);
  float* cc   = (float*)((char*)d_ws + WS_CC);
  unsigned short* cbs = (unsigned short*)((char*)d_ws + WS_CBS);

  vq_prep<<<1024, 256, 0, stream>>>(cb, cc, cbs, loss);
  VQQuantizer_30064771072206_kernel<<<1024, 256, 0, stream>>>(z, cb, cbs, cc, loss, out);
  vq_finalize<<<1, 1, 0, stream>>>(loss, out);
}

// Round 13
// 248.773 us; speedup vs baseline: 1.2538x; 1.2538x over previous
//
#include <hip/hip_runtime.h>

typedef short s16x8 __attribute__((ext_vector_type(8)));  // 8 bf16
typedef float f32x4 __attribute__((ext_vector_type(4)));  // 16x16 MFMA acc

#define CODES_ELEMS 8388608   // 16*1024*512
#define N_ROWS      131072    // 16*1024*8
#define IDX_OFF     CODES_ELEMS
#define LOSS_OFF    (CODES_ELEMS + N_ROWS)

// d_ws: [0,4) loss acc; [64,8256) cc[2048];
// [8448,532736) cbs bf16-split tiled codebook [chunk32][seg4][ct4][lane64][8]
//   seg 0,1 = c1 dims 0-31/32-63; seg 2,3 = c2 exact residual dims 0-31/32-63
#define WS_LOSS 0
#define WS_CC   64
#define WS_CBS  8448
// validated r13-r21 (absmax 0 x9): packed-min + margin + offset constants
#define MARGIN_T 0.0625f
#define DIST_OFF 512.0f

__device__ __forceinline__ float bf2f(unsigned short h) { return __uint_as_float(((unsigned)h) << 16); }
__device__ __forceinline__ unsigned short f2bf(float f) {   // RNE
  unsigned u = __float_as_uint(f);
  u += 0x7fffu + ((u >> 16) & 1u);
  return (unsigned short)(u >> 16);
}

// Prep (validated r16-r21): bf16-split codebook into 16x16x32 B-fragment
// layout (chunk 64 codes / ct-width 4) + cc[k] butterfly.
__global__ __launch_bounds__(256) void vq_prep(const float* __restrict__ cb,
                                               float* __restrict__ cc,
                                               unsigned short* __restrict__ cbs,
                                               float* __restrict__ loss) {
  int t = threadIdx.x;
  if (blockIdx.x == 0 && t == 0) loss[0] = 0.f;
  int e = blockIdx.x * 256 + t;   // 1024*256 = 2048 codes * 128 K-elems
  int k = e >> 7, K = e & 127;
  int s = K >> 5, rem = K & 31, q = rem >> 3, j = rem & 7;
  int d = (s < 2) ? K : (K - 64);
  float c = cb[k * 64 + d];
  unsigned short c1 = f2bf(c);
  unsigned short val = (s < 2) ? c1 : f2bf(c - bf2f(c1));  // exact residual split
  int chunk = k >> 6, ct = (k >> 4) & 3, n = k & 15;
  cbs[(((size_t)(chunk * 4 + s) * 4 + ct) * 64 + (q * 16 + n)) * 8 + j] = val;
  float sq = c * c;
  #pragma unroll
  for (int m = 1; m < 64; m <<= 1) sq += __shfl_xor(sq, m, 64);
  if ((t & 63) == 0) cc[k] = sq;
}

// group g (0..127) = (chunk g>>2, ct g&3); frag s at (g>>2)*8192+(g&3)*512+s*2048
#define LOADB(D0, D1, D2, D3, G) {                                            \
  const unsigned short* _p = cbs + (size_t)((G) >> 2) * 8192                  \
                               + (size_t)((G) & 3) * 512 + (size_t)l * 8;     \
  D0 = *(const s16x8*)(_p + 0 * 2048);                                        \
  D1 = *(const s16x8*)(_p + 1 * 2048);                                        \
  D2 = *(const s16x8*)(_p + 2 * 2048);                                        \
  D3 = *(const s16x8*)(_p + 3 * 2048); }

#define COMPUTE_GROUP(B0, B1, B2, B3, G) {                                    \
  float nh = DIST_OFF + cc_l[(G) * 16 + col];                                 \
  unsigned pid = (unsigned)(G);                                               \
  _Pragma("unroll")                                                           \
  for (int tile = 0; tile < 4; ++tile) {                                      \
    f32x4 acc; acc[0] = nh; acc[1] = nh; acc[2] = nh; acc[3] = nh;            \
    acc = __builtin_amdgcn_mfma_f32_16x16x32_bf16(az1[tile][0], B0, acc, 0, 0, 0); \
    acc = __builtin_amdgcn_mfma_f32_16x16x32_bf16(az1[tile][1], B1, acc, 0, 0, 0); \
    acc = __builtin_amdgcn_mfma_f32_16x16x32_bf16(az1[tile][0], B2, acc, 0, 0, 0); \
    acc = __builtin_amdgcn_mfma_f32_16x16x32_bf16(az1[tile][1], B3, acc, 0, 0, 0); \
    acc = __builtin_amdgcn_mfma_f32_16x16x32_bf16(az2[tile][0], B0, acc, 0, 0, 0); \
    acc = __builtin_amdgcn_mfma_f32_16x16x32_bf16(az2[tile][1], B1, acc, 0, 0, 0); \
    _Pragma("unroll")                                                         \
    for (int r = 0; r < 4; ++r) {                                             \
      unsigned pd = (__float_as_uint(acc[r]) & 0xFFFFFF80u) | pid;            \
      unsigned mx = p1[tile][r] > pd ? p1[tile][r] : pd;                      \
      p2[tile][r] = p2[tile][r] < mx ? p2[tile][r] : mx;                      \
      p1[tile][r] = p1[tile][r] < pd ? p1[tile][r] : pd;                      \
    }                                                                         \
  } }

// Mega-kernel r22 = r20 (best measured: 193us main, VGPR 96, no spill) with
// the K-loop's serial load->waitcnt->MFMA chain software-pipelined: B-frags
// double-buffered in REGISTERS one code-group ahead (g+1's 4 loads issue
// before g's 24 MFMAs; the waitcnt at g+1's consume finds them landed).
// r21's falsifier fired: TLP (16 waves/CU) did NOT raise MfmaUtil -> the
// per-ct load latency was the limiter, not wave count. No barriers, no LDS
// for B; buffers alternate by g parity (static names). Tail = r17-validated.
__global__ __launch_bounds__(256) void VQQuantizer_30064771072206_kernel(
    const float* __restrict__ zf, const float* __restrict__ cb,
    const unsigned short* __restrict__ cbs, const float* __restrict__ cc,
    float* __restrict__ loss, float* __restrict__ out)
{
  __shared__ __align__(16) float cc_l[2048];     // 8KB, read in K-loop + rescore
  __shared__ int   idx_l[256];
  __shared__ int   flg[256];
  __shared__ int   nf;
  __shared__ __align__(16) float zl[8][68];
  __shared__ float zz_l[8];
  __shared__ int   rows_s[8];
  __shared__ float rv[4][8];
  __shared__ int   ri[4][8];
  __shared__ float wsum[4];

  const int t = threadIdx.x, w = t >> 6, l = t & 63;
  const int col = l & 15, q = l >> 4;
  const int R0 = blockIdx.x * 256;
  const float4* zf4 = (const float4*)zf;
  const float4* cb4 = (const float4*)cb;

  // prologue: load full cc into LDS
  #pragma unroll
  for (int i = 0; i < 2; ++i)
    ((float4*)cc_l)[i * 256 + t] = ((const float4*)cc)[i * 256 + t];

  // A-fragments (r12-validated): lane holds A[m=l&15][k=q*8+j]; per tile
  // row = R0 + tile*64 + 16w + col; seg s covers dims s*32 + q*8 + j.
  s16x8 az1[4][2], az2[4][2];   // [tile][seg]: bf16(-2z) and exact residual
  #pragma unroll
  for (int tile = 0; tile < 4; ++tile) {
    int row = R0 + tile * 64 + 16 * w + col;
    const float4* zr = zf4 + (size_t)row * 16;
    #pragma unroll
    for (int s = 0; s < 2; ++s) {
      float4 u0 = zr[s * 8 + q * 2];
      float4 u1 = zr[s * 8 + q * 2 + 1];
      float m2[8] = {-2.f*u0.x, -2.f*u0.y, -2.f*u0.z, -2.f*u0.w,
                     -2.f*u1.x, -2.f*u1.y, -2.f*u1.z, -2.f*u1.w};
      #pragma unroll
      for (int j = 0; j < 8; ++j) {
        unsigned short h1 = f2bf(m2[j]);
        unsigned short h2 = f2bf(m2[j] - bf2f(h1));
        az1[tile][s][j] = (short)h1;
        az2[tile][s][j] = (short)h2;
      }
    }
  }

  unsigned p1[4][4], p2[4][4];   // packed (trunc dist | pid): best / second
  #pragma unroll
  for (int tile = 0; tile < 4; ++tile)
    #pragma unroll
    for (int r = 0; r < 4; ++r) { p1[tile][r] = 0xFFFFFFFFu; p2[tile][r] = 0xFFFFFFFFu; }

  __syncthreads();   // cc_l visible (the ONLY barrier before phase 2)

  // ---- K-loop: barrier-free, register-double-buffered B prefetch ----
  s16x8 bA0, bA1, bA2, bA3, bB0, bB1, bB2, bB3;
  LOADB(bA0, bA1, bA2, bA3, 0);
  #pragma unroll 1
  for (int g = 0; g < 128; g += 2) {
    LOADB(bB0, bB1, bB2, bB3, g + 1);            // issue next-group loads
    COMPUTE_GROUP(bA0, bA1, bA2, bA3, g);        // 24 MFMA hide their latency
    if (g + 2 < 128) LOADB(bA0, bA1, bA2, bA3, g + 2);
    COMPUTE_GROUP(bB0, bB1, bB2, bB3, g + 1);
  }

  // ---- phase 2: unpack + merge across the 16 lanes of each row group ----
  if (t == 0) nf = 0;
  __syncthreads();
  #pragma unroll
  for (int tile = 0; tile < 4; ++tile) {
    #pragma unroll
    for (int r = 0; r < 4; ++r) {
      float a   = __uint_as_float(p1[tile][r] & 0xFFFFFF80u);
      int   ia  = (int)(p1[tile][r] & 127u) * 16 + col;   // code = pid*16 + col
      float b2v = __uint_as_float(p2[tile][r] & 0xFFFFFF80u);
      #pragma unroll
      for (int m = 1; m < 16; m <<= 1) {
        float oa = __shfl_xor(a, m, 64);
        int   oi = __shfl_xor(ia, m, 64);
        float ob = __shfl_xor(b2v, m, 64);
        float hv = fmaxf(a, oa);
        b2v = fminf(fminf(b2v, ob), hv);
        bool take = (oa < a) || (oa == a && oi < ia);
        a = take ? oa : a; ia = take ? oi : ia;
      }
      if (col == 0) {   // C/D: col=l&15, row=(l>>4)*4+r [m89, validated]
        int rl = tile * 64 + 16 * w + q * 4 + r;
        idx_l[rl] = ia;
        if (b2v - a < MARGIN_T) {
          int p = atomicAdd(&nf, 1);
          flg[p] = rl;
        }
      }
    }
  }
  __syncthreads();

  // ---- phase 3: exact fp32 rescore of flagged rows (validated inner chain;
  //      dq-loop unroll capped at 4 to keep register pressure below K-loop) ----
  int count = nf;
  for (int itb = 0; itb * 8 < count; ++itb) {
    if (itb) __syncthreads();
    if (t < 8) {
      int ii = itb * 8 + t;
      rows_s[t] = flg[ii < count ? ii : count - 1];  // tail dup: benign rewrite
    }
    __syncthreads();
    if (t < 128) {
      int r = t >> 4, dq = t & 15;
      *(float4*)&zl[r][dq * 4] = zf4[(size_t)(R0 + rows_s[r]) * 16 + dq];
    }
    __syncthreads();
    if (t < 8) {                          // zz: sequential-d np chain
      float s = 0.f;
      for (int d = 0; d < 64; ++d) { float v = zl[t][d]; s += v * v; }
      zz_l[t] = s;
    }
    __syncthreads();

    float bv[8]; int bi[8];
    #pragma unroll
    for (int r = 0; r < 8; ++r) { bv[r] = 3.402823466e38f; bi[r] = 0; }
    #pragma unroll 1
    for (int o = 0; o < 8; ++o) {         // thread's codes ascending: o*256+t
      int c = o * 256 + t;
      const float4* cr = cb4 + (size_t)c * 16;
      float a[8];
      #pragma unroll
      for (int r = 0; r < 8; ++r) a[r] = 0.f;
      #pragma unroll 4                    // cap hoisted cv regs
      for (int dq = 0; dq < 16; ++dq) {
        float4 cv = cr[dq];
        #pragma unroll
        for (int r = 0; r < 8; ++r) {
          float4 z4 = *(const float4*)&zl[r][dq * 4];
          a[r] += z4.x * cv.x;
          a[r] += z4.y * cv.y;
          a[r] += z4.z * cv.z;
          a[r] += z4.w * cv.w;
        }
      }
      float ccv = cc_l[c];
      #pragma unroll
      for (int r = 0; r < 8; ++r) {
        float t0 = zz_l[r] - 2.0f * a[r];
        float dist = t0 + ccv;
        if (dist < bv[r]) { bv[r] = dist; bi[r] = c; }
      }
    }
    #pragma unroll
    for (int r = 0; r < 8; ++r) {
      float v = bv[r]; int idx = bi[r];
      #pragma unroll
      for (int m = 1; m < 64; m <<= 1) {
        float ov = __shfl_xor(v, m, 64); int oi = __shfl_xor(idx, m, 64);
        if (ov < v || (ov == v && oi < idx)) { v = ov; idx = oi; }
      }
      if (l == 0) { rv[w][r] = v; ri[w][r] = idx; }
    }
    __syncthreads();
    if (t < 8) {
      float fv = rv[0][t]; int fi = ri[0][t];
      #pragma unroll
      for (int k = 1; k < 4; ++k) {
        if (rv[k][t] < fv || (rv[k][t] == fv && ri[k][t] < fi)) { fv = rv[k][t]; fi = ri[k][t]; }
      }
      idx_l[rows_s[t]] = fi;
    }
  }
  __syncthreads();

  // ---- phase 4: epilogue for this block's 256 rows (unroll capped, r17) ----
  float4* out4 = (float4*)out;
  float lsum = 0.f;
  #pragma unroll 2
  for (int i = 0; i < 16; ++i) {
    int f = i * 256 + t;
    int row = f >> 4, dq = f & 15;
    int k = idx_l[row];
    float4 qv = cb4[(size_t)k * 16 + dq];
    float4 zv = zf4[(size_t)(R0 + row) * 16 + dq];
    float dx = qv.x - zv.x, dy = qv.y - zv.y, dz = qv.z - zv.z, dw = qv.w - zv.w;
    float4 st; st.x = zv.x + dx; st.y = zv.y + dy; st.z = zv.z + dz; st.w = zv.w + dw;
    out4[(size_t)(R0 + row) * 16 + dq] = st;
    lsum += dx * dx; lsum += dy * dy; lsum += dz * dz; lsum += dw * dw;
  }
  out[IDX_OFF + R0 + t] = (float)idx_l[t];
  #pragma unroll
  for (int m = 1; m < 64; m <<= 1) lsum += __shfl_xor(lsum, m, 64);
  if (l == 0) wsum[w] = lsum;
  __syncthreads();
  if (t == 0) atomicAdd(loss, wsum[0] + wsum[1] + wsum[2] + wsum[3]);
}

__global__ void vq_finalize(const float* __restrict__ loss, float* __restrict__ out) {
  out[LOSS_OFF] = loss[0] * (1.f / 8388608.f);
}

extern "C" void kernel_launch(void* const* d_in, const int* in_sizes, int n_in,
                              void* d_out, int out_size, void* d_ws, size_t ws_size,
                              hipStream_t stream) {
  const float* z  = (const float*)d_in[0];
  const float* cb = (const float*)d_in[1];
  float* out = (float*)d_out;
  float* loss = (float*)((char*)d_ws + WS_LOSS);
  float* cc   = (float*)((char*)d_ws + WS_CC);
  unsigned short* cbs = (unsigned short*)((char*)d_ws + WS_CBS);

  vq_prep<<<1024, 256, 0, stream>>>(cb, cc, cbs, loss);
  VQQuantizer_30064771072206_kernel<<<512, 256, 0, stream>>>(z, cb, cbs, cc, loss, out);
  vq_finalize<<<1, 1, 0, stream>>>(loss, out);
}